// Round 1
// baseline (4016.746 us; speedup 1.0000x reference)
//
#include <hip/hip_runtime.h>
#include <hip/hip_bf16.h>

#define BB 8
#define HH 256
#define WW 256
#define HW 65536

// ---------------------------------------------------------------------------
// Kernel A: x_gauss = grouped conv(x, w_gauss, pad=10, groups=3) -> (8,66,256,256)
// output channel o: input channel o/22, kernel w_gauss[o] (support ks x ks, zero outside)
// Stored bf16 in workspace. Tile: 128(w) x 8(h) per block, thread = 4 consecutive w.
// ---------------------------------------------------------------------------
__global__ __launch_bounds__(256) void k_xgauss(const float* __restrict__ x,
                                                const float* __restrict__ wg,
                                                __hip_bfloat16* __restrict__ xg) {
  const int bo = blockIdx.z;
  const int b = bo / 66, o = bo % 66;
  const int h0 = blockIdx.y * 8, w0 = blockIdx.x * 128;
  const int g = o / 22;     // input channel (feature_group_count=3)
  const int kidx = o / 3;   // w_gauss[o] = w_orig[o//3] (np.repeat axis 0)
  __shared__ float wl[441];
  __shared__ float xt[28 * 148];
  for (int e = threadIdx.x; e < 441; e += 256) wl[e] = wg[o * 441 + e];
  const float* xp = x + (b * 3 + g) * HW;
  for (int e = threadIdx.x; e < 28 * 148; e += 256) {
    int ty = e / 148, tx = e % 148;
    int gy = h0 + ty - 10, gx = w0 + tx - 10;
    xt[e] = (gy >= 0 && gy < HH && gx >= 0 && gx < WW) ? xp[gy * WW + gx] : 0.f;
  }
  __syncthreads();
  // support size of kernel kidx: 1 for identity, else 3,3,3,5,5,7,7,...,21,21
  int i_ = kidx - 1;
  int im = (i_ - 1 > 0) ? (i_ - 1) : 0;
  int ks = (kidx == 0) ? 1 : 3 + 2 * (im >> 1);
  int p0 = (21 - ks) >> 1;
  const int wq = threadIdx.x & 31, r = threadIdx.x >> 5;
  float a0 = 0.f, a1 = 0.f, a2 = 0.f, a3 = 0.f;
  for (int kh = p0; kh < p0 + ks; ++kh) {   // rows outside support are all-zero
    float rx[24];
    const float4* rp = (const float4*)&xt[(r + kh) * 148 + 4 * wq];
    float4* rv = (float4*)rx;
#pragma unroll
    for (int i = 0; i < 6; i++) rv[i] = rp[i];
    const float* wr = &wl[kh * 21];
#pragma unroll
    for (int kw = 0; kw < 21; kw++) {       // zero weights outside support: harmless
      float wv = wr[kw];
      a0 += wv * rx[kw];     a1 += wv * rx[kw + 1];
      a2 += wv * rx[kw + 2]; a3 += wv * rx[kw + 3];
    }
  }
  int oidx = ((b * 66 + o) * HH + (h0 + r)) * WW + w0 + 4 * wq;
  xg[oidx]     = __float2bfloat16(a0);
  xg[oidx + 1] = __float2bfloat16(a1);
  xg[oidx + 2] = __float2bfloat16(a2);
  xg[oidx + 3] = __float2bfloat16(a3);
}

// ---------------------------------------------------------------------------
// Kernel B: predictor stage 1: leaky(conv11x11(x)+b) then adaptive 3x3 pool.
// Output spatial is 250x250; bins are [0,84),[83,167),[166,250) both dims.
// Block = one (b, bin, 8-channel group); threads stride over the 84x84 positions.
// ---------------------------------------------------------------------------
__global__ __launch_bounds__(256) void k_pred1(const float* __restrict__ x,
                                               const float* __restrict__ p1w,
                                               const float* __restrict__ p1b,
                                               float* __restrict__ pooled) {
  const int cb = blockIdx.x, bin = blockIdx.y, b = blockIdx.z;
  const int bi = bin / 3, bj = bin % 3;
  const int hs = (bi * 250) / 3, ws0 = (bj * 250) / 3;  // each bin is 84 long
  __shared__ float wl[363 * 8];  // [k][c] transposed for float4 broadcast
  __shared__ float bl[8];
  __shared__ float red[256];
  for (int e = threadIdx.x; e < 363 * 8; e += 256) {
    int k = e >> 3, c = e & 7;
    wl[e] = p1w[(cb * 8 + c) * 363 + k];
  }
  if (threadIdx.x < 8) bl[threadIdx.x] = p1b[cb * 8 + threadIdx.x];
  __syncthreads();
  const float* xb = x + b * 3 * HW;
  float pool[8] = {0.f,0.f,0.f,0.f,0.f,0.f,0.f,0.f};
  for (int p = threadIdx.x; p < 7056; p += 256) {
    int ph = p / 84, pw = p % 84;
    int h = hs + ph, w = ws0 + pw;
    float cv[8] = {0.f,0.f,0.f,0.f,0.f,0.f,0.f,0.f};
    for (int ci = 0; ci < 3; ci++) {
      const float* xc = xb + ci * HW;
      for (int kh = 0; kh < 11; kh++) {
        int iy = h - 2 + kh;              // pad=2
        if (iy < 0 || iy >= HH) continue;
        const float* xr = xc + iy * WW;
        const float* wk = &wl[(ci * 121 + kh * 11) * 8];
#pragma unroll
        for (int kw = 0; kw < 11; kw++) {
          int ix = w - 2 + kw;
          if (ix >= 0 && ix < WW) {
            float xv = xr[ix];
            const float4* w4 = (const float4*)&wk[kw * 8];
            float4 wa = w4[0], wb2 = w4[1];
            cv[0] += xv * wa.x;  cv[1] += xv * wa.y;
            cv[2] += xv * wa.z;  cv[3] += xv * wa.w;
            cv[4] += xv * wb2.x; cv[5] += xv * wb2.y;
            cv[6] += xv * wb2.z; cv[7] += xv * wb2.w;
          }
        }
      }
    }
#pragma unroll
    for (int c = 0; c < 8; c++) {
      float z = cv[c] + bl[c];
      pool[c] += (z >= 0.f) ? z : 0.2f * z;   // leaky_relu(0.2) before pooling
    }
  }
  const float inv = 1.f / 7056.f;
  for (int c = 0; c < 8; c++) {
    __syncthreads();
    red[threadIdx.x] = pool[c];
    __syncthreads();
    for (int s = 128; s > 0; s >>= 1) {
      if (threadIdx.x < s) red[threadIdx.x] += red[threadIdx.x + s];
      __syncthreads();
    }
    if (threadIdx.x == 0)
      pooled[((b * 128 + cb * 8 + c) * 3 + bi) * 3 + bj] = red[0] * inv;
  }
}

// ---------------------------------------------------------------------------
// Kernel C: predictor tail. p2 (1x1,128->441)+leaky, pool (3,1), p3 (1x1,441->441),
// softmax over 441 channels per spatial row, write kern_flat[f]=soft[f/3][f%3].
// One block per sample.
// ---------------------------------------------------------------------------
__global__ __launch_bounds__(256) void k_pred2(const float* __restrict__ pooled,
                                               const float* __restrict__ p2w,
                                               const float* __restrict__ p3w,
                                               float* __restrict__ kernw) {
  const int b = blockIdx.x;
  const int tid = threadIdx.x;
  __shared__ float hin[1152];   // 128 x 9
  __shared__ float h2p[1323];   // 441 x 3
  __shared__ float h3l[1323];   // 441 x 3
  __shared__ float mx[3], sm[3];
  for (int e = tid; e < 1152; e += 256) hin[e] = pooled[b * 1152 + e];
  __syncthreads();
  for (int c = tid; c < 441; c += 256) {
    float z[9] = {0.f,0.f,0.f,0.f,0.f,0.f,0.f,0.f,0.f};
    const float* wr = p2w + c * 128;
    for (int k = 0; k < 128; k++) {
      float wv = wr[k];
      const float* hp = &hin[k * 9];
#pragma unroll
      for (int p = 0; p < 9; p++) z[p] += wv * hp[p];
    }
#pragma unroll
    for (int i = 0; i < 3; i++) {
      float s = 0.f;
#pragma unroll
      for (int jj = 0; jj < 3; jj++) {
        float zz = z[i * 3 + jj];
        s += (zz >= 0.f) ? zz : 0.2f * zz;
      }
      h2p[c * 3 + i] = s * (1.f / 3.f);  // adaptive pool (3,1): mean over the 3 cols
    }
  }
  __syncthreads();
  for (int c = tid; c < 441; c += 256) {
    float a0 = 0.f, a1 = 0.f, a2 = 0.f;
    const float* wr = p3w + c * 441;
    for (int k = 0; k < 441; k++) {
      float wv = wr[k];
      a0 += wv * h2p[k * 3];
      a1 += wv * h2p[k * 3 + 1];
      a2 += wv * h2p[k * 3 + 2];
    }
    h3l[c * 3] = a0; h3l[c * 3 + 1] = a1; h3l[c * 3 + 2] = a2;
  }
  __syncthreads();
  if (tid < 3) {
    float m = -1e30f;
    for (int c = 0; c < 441; c++) m = fmaxf(m, h3l[c * 3 + tid]);
    float s = 0.f;
    for (int c = 0; c < 441; c++) s += expf(h3l[c * 3 + tid] - m);
    mx[tid] = m; sm[tid] = 1.f / s;
  }
  __syncthreads();
  for (int f = tid; f < 1323; f += 256) {
    int i = f % 3;  // f = c*3 + s; kern reshape consumes this flat order directly
    kernw[b * 1323 + f] = expf(h3l[f] - mx[i]) * sm[i];
  }
}

// ---------------------------------------------------------------------------
// Kernel D: per-sample dynamic conv: out1[b] = sum_i corr21x21(x[b,i], kern[b,i])
// Tile 64(w) x 16(h); thread = 4 consecutive w.
// ---------------------------------------------------------------------------
__global__ __launch_bounds__(256) void k_dyn(const float* __restrict__ x,
                                             const float* __restrict__ kernw,
                                             float* __restrict__ out1) {
  const int b = blockIdx.z;
  const int h0 = blockIdx.y * 16, w0 = blockIdx.x * 64;
  __shared__ float kl[1323];
  __shared__ float xt[3 * 36 * 84];
  for (int e = threadIdx.x; e < 1323; e += 256) kl[e] = kernw[b * 1323 + e];
  for (int e = threadIdx.x; e < 3 * 36 * 84; e += 256) {
    int ci = e / 3024, rem = e % 3024;
    int ty = rem / 84, tx = rem % 84;
    int gy = h0 + ty - 10, gx = w0 + tx - 10;
    xt[e] = (gy >= 0 && gy < HH && gx >= 0 && gx < WW)
                ? x[(b * 3 + ci) * HW + gy * WW + gx] : 0.f;
  }
  __syncthreads();
  const int wq = threadIdx.x & 15, r = threadIdx.x >> 4;
  float a0 = 0.f, a1 = 0.f, a2 = 0.f, a3 = 0.f;
  for (int ci = 0; ci < 3; ci++) {
    for (int kh = 0; kh < 21; kh++) {
      float rx[24];
      const float4* rp = (const float4*)&xt[ci * 3024 + (r + kh) * 84 + 4 * wq];
      float4* rv = (float4*)rx;
#pragma unroll
      for (int i = 0; i < 6; i++) rv[i] = rp[i];
      const float* wr = &kl[ci * 441 + kh * 21];
#pragma unroll
      for (int kw = 0; kw < 21; kw++) {
        float wv = wr[kw];
        a0 += wv * rx[kw];     a1 += wv * rx[kw + 1];
        a2 += wv * rx[kw + 2]; a3 += wv * rx[kw + 3];
      }
    }
  }
  int idx = b * HW + (h0 + r) * WW + w0 + 4 * wq;
  *(float4*)&out1[idx] = make_float4(a0, a1, a2, a3);
}

// ---------------------------------------------------------------------------
// Kernel E: ax_out = conv3x3(x, cs_w) + cs_b  -> second output
// ---------------------------------------------------------------------------
__global__ __launch_bounds__(256) void k_ax(const float* __restrict__ x,
                                            const float* __restrict__ csw,
                                            const float* __restrict__ csb,
                                            float* __restrict__ out2) {
  int idx = blockIdx.x * 256 + threadIdx.x;
  if (idx >= BB * 3 * HW) return;
  int w = idx & 255, h = (idx >> 8) & 255;
  int oc = (idx >> 16) % 3, b = idx / (3 * HW);
  float acc = csb[oc];
  for (int ic = 0; ic < 3; ic++) {
    const float* xc = x + (b * 3 + ic) * HW;
    const float* wp = csw + (oc * 3 + ic) * 9;
#pragma unroll
    for (int u = 0; u < 3; u++) {
      int iy = h + u - 1;
      if (iy < 0 || iy >= HH) continue;
#pragma unroll
      for (int v = 0; v < 3; v++) {
        int ix = w + v - 1;
        if (ix >= 0 && ix < WW) acc += xc[iy * WW + ix] * wp[u * 3 + v];
      }
    }
  }
  out2[idx] = acc;
}

// ---------------------------------------------------------------------------
// Kernel G: fused = conv3x3(concat[x_gauss, x_af], fu_w) + fu_b.
// x_af is recomputed per tile from out1: x_af[c'] = corr3x3(out1, sum_c tr_w[c',c]) + tr_b[c']
// (the 3 channels of `output` are identical). Tile 32x32, thread = 4 px x 16 outch,
// input channels staged in LDS 8 at a time.
// ---------------------------------------------------------------------------
__global__ __launch_bounds__(256) void k_fused(const __hip_bfloat16* __restrict__ xg,
                                               const float* __restrict__ out1,
                                               const float* __restrict__ trw,
                                               const float* __restrict__ trb,
                                               const float* __restrict__ fuw,
                                               const float* __restrict__ fub,
                                               float* __restrict__ outf) {
  const int bz = blockIdx.z;
  const int b = bz / 5, ob = bz % 5;
  const int o0 = ob * 16;
  const int h0 = blockIdx.y * 32, w0 = blockIdx.x * 32;
  __shared__ float trs[594];     // 66 x 9 channel-summed tr_w
  __shared__ float trbl[66];
  __shared__ float o1t[36 * 37]; // out1 tile with 2-halo (padded stride)
  __shared__ float xt[8 * 1190]; // 8ch x 34 x (stride 35) input tile
  __shared__ float wl[1152];     // 8ch x 9tap x 16outch
  const int tid = threadIdx.x;
  for (int e = tid; e < 594; e += 256) {
    int cp = e / 9, k = e % 9;
    trs[e] = trw[(cp * 3 + 0) * 9 + k] + trw[(cp * 3 + 1) * 9 + k] + trw[(cp * 3 + 2) * 9 + k];
  }
  if (tid < 66) trbl[tid] = trb[tid];
  for (int e = tid; e < 36 * 36; e += 256) {
    int ty = e / 36, tx = e % 36;
    int gy = h0 - 2 + ty, gx = w0 - 2 + tx;
    o1t[ty * 37 + tx] = (gy >= 0 && gy < HH && gx >= 0 && gx < WW)
                            ? out1[b * HW + gy * WW + gx] : 0.f;
  }
  float acc[4][16];
#pragma unroll
  for (int j = 0; j < 4; j++)
#pragma unroll
    for (int q = 0; q < 16; q++) acc[j][q] = 0.f;
  const int r = tid >> 3, g = tid & 7;
  const int wb = 4 * g;
  for (int c0 = 0; c0 < 132; c0 += 8) {
    __syncthreads();  // also covers trs/o1t on first pass, prior compute on later passes
    for (int e = tid; e < 8 * 34 * 34; e += 256) {
      int cc = e / 1156, rem = e % 1156;
      int ty = rem / 34, tx = rem % 34;
      int c = c0 + cc;
      int gy = h0 - 1 + ty, gx = w0 - 1 + tx;
      float v = 0.f;
      if (c < 132 && gy >= 0 && gy < HH && gx >= 0 && gx < WW) {
        if (c < 66) {
          v = __bfloat162float(xg[(b * 66 + c) * HW + gy * WW + gx]);
        } else {
          int cp = c - 66;
          const float* tp = &trs[cp * 9];
          float s = trbl[cp];
#pragma unroll
          for (int u = 0; u < 3; u++)
#pragma unroll
            for (int vv = 0; vv < 3; vv++)
              s += o1t[(ty + u) * 37 + (tx + vv)] * tp[u * 3 + vv];
          v = s;
        }
      }
      xt[cc * 1190 + ty * 35 + tx] = v;
    }
    for (int e = tid; e < 1152; e += 256) {
      int cc = e / 144, k = (e % 144) / 16, oo = e & 15;
      int o = o0 + oo, c = c0 + cc;
      wl[e] = (o < 66 && c < 132) ? fuw[(o * 132 + c) * 9 + k] : 0.f;
    }
    __syncthreads();
#pragma unroll 1
    for (int cc = 0; cc < 8; cc++) {
      const float* xrow = &xt[cc * 1190];
      const float* wc = &wl[cc * 144];
#pragma unroll
      for (int u = 0; u < 3; u++) {
        float xv[6];
        const float* rp = &xrow[(r + u) * 35 + wb];
#pragma unroll
        for (int m = 0; m < 6; m++) xv[m] = rp[m];
#pragma unroll
        for (int v = 0; v < 3; v++) {
          const float4* w4 = (const float4*)&wc[(u * 3 + v) * 16];
#pragma unroll
          for (int q = 0; q < 4; q++) {
            float4 wv = w4[q];
#pragma unroll
            for (int j = 0; j < 4; j++) {
              float xj = xv[j + v];
              acc[j][q * 4 + 0] += xj * wv.x;
              acc[j][q * 4 + 1] += xj * wv.y;
              acc[j][q * 4 + 2] += xj * wv.z;
              acc[j][q * 4 + 3] += xj * wv.w;
            }
          }
        }
      }
    }
  }
  const int on = (o0 + 16 <= 66) ? 16 : 66 - o0;
  for (int oo = 0; oo < on; oo++) {
    float bias = fub[o0 + oo];
    float4 v4 = make_float4(acc[0][oo] + bias, acc[1][oo] + bias,
                            acc[2][oo] + bias, acc[3][oo] + bias);
    int idx = (b * 66 + o0 + oo) * HW + (h0 + r) * WW + w0 + wb;
    *(float4*)&outf[idx] = v4;
  }
}

// ---------------------------------------------------------------------------
extern "C" void kernel_launch(void* const* d_in, const int* in_sizes, int n_in,
                              void* d_out, int out_size, void* d_ws, size_t ws_size,
                              hipStream_t stream) {
  const float* x   = (const float*)d_in[0];
  const float* wg  = (const float*)d_in[1];
  const float* p1w = (const float*)d_in[2];
  const float* p1b = (const float*)d_in[3];
  const float* p2w = (const float*)d_in[4];
  const float* p3w = (const float*)d_in[5];
  const float* csw = (const float*)d_in[6];
  const float* csb = (const float*)d_in[7];
  const float* trw = (const float*)d_in[8];
  const float* trb = (const float*)d_in[9];
  const float* fuw = (const float*)d_in[10];
  const float* fub = (const float*)d_in[11];
  float* outf = (float*)d_out;                 // fused: 8*66*256*256
  float* out2 = outf + 34603008;               // ax_out: 8*3*256*256
  char* ws = (char*)d_ws;
  __hip_bfloat16* xg = (__hip_bfloat16*)ws;    // 69,206,016 B
  float* out1   = (float*)(ws + 69206016);     // 2,097,152 B
  float* pooled = (float*)(ws + 71303168);     // 36,864 B
  float* kernw  = (float*)(ws + 71340032);     // 42,336 B

  hipLaunchKernelGGL(k_xgauss, dim3(2, 32, 8 * 66), dim3(256), 0, stream, x, wg, xg);
  hipLaunchKernelGGL(k_pred1,  dim3(16, 9, 8),      dim3(256), 0, stream, x, p1w, p1b, pooled);
  hipLaunchKernelGGL(k_pred2,  dim3(8),             dim3(256), 0, stream, pooled, p2w, p3w, kernw);
  hipLaunchKernelGGL(k_dyn,    dim3(4, 16, 8),      dim3(256), 0, stream, x, kernw, out1);
  hipLaunchKernelGGL(k_ax,     dim3(6144),          dim3(256), 0, stream, x, csw, csb, out2);
  hipLaunchKernelGGL(k_fused,  dim3(8, 8, 40),      dim3(256), 0, stream, xg, out1, trw, trb, fuw, fub, outf);
}

// Round 2
// 1896.568 us; speedup vs baseline: 2.1179x; 2.1179x over previous
//
#include <hip/hip_runtime.h>
#include <hip/hip_bf16.h>

#define BB 8
#define HH 256
#define WW 256
#define HW 65536

typedef __attribute__((ext_vector_type(8))) short bf16x8;
typedef __attribute__((ext_vector_type(4))) float f32x4;
#define MFMA16(a, b, c) __builtin_amdgcn_mfma_f32_16x16x32_bf16(a, b, c, 0, 0, 0)

__device__ __forceinline__ ushort f2bf(float f) {
  union { float f; uint32_t u; } c; c.f = f;
  uint32_t r = (c.u + 0x7fffu + ((c.u >> 16) & 1u)) >> 16;
  return (ushort)r;
}

// ---------------- workspace layout (bytes) ----------------
#define OFF_XG    0            // xg NCHW bf16:  8*66*65536*2   = 69,206,016
#define OFF_XGN   69206016     // xg NHWC bf16 (72ch padded):   = 75,497,472
#define OFF_OUT1  144703488    // out1 f32: 8*65536*4           = 2,097,152
#define OFF_POOL  146800640    // pooled sums f32: 8*128*9*4    = 36,864
#define OFF_KERN  146837504    // kern f32: 8*1323*4            = 42,336 (+pad)
#define OFF_BW    146880000    // Bw bf16: 2*9*80*32*2 stored as 3*9*80*32? -> [cc(2)][t9][o80][32]; alloc 138,240
#define OFF_BWZ   147018240    // BwZ bf16: 2*80*32*2           = 10,240
#define OFF_BP    147028480    // Bp bf16: 12*128*32*2          = 98,304
#define OFF_BIAS  147126784    // bias_tot f32: 80*4 (+pad)
#define OFF_TB    147127296    // TB f32: 66*9*4 (+pad)
#define OFF_T     147129856    // T f32: 66*81*4 (+pad)
#define OFF_OFFP  147151360    // offp i32: 384*4

// ---------------------------------------------------------------------------
// prepA: T, TB, Bw (gauss-chunk weights), Bp (pred1 weights), offp (im2col LUT)
//   T[o][a][s]  = sum_cp fuw[o][66+cp][a] * trs[cp][s],  trs = sum_ic trw
//   TB[o][a]    = sum_cp trb[cp] * fuw[o][66+cp][a]
//   Bw[cc][t][o][kl] = fuw[o][cc*32+kl][t]  (bf16, o<66 else 0)
//   Bp[kc][o][kl]    = p1w[o][c][u][v], k = u*33+v*3+c
// ---------------------------------------------------------------------------
__global__ __launch_bounds__(256) void k_prepA(const float* __restrict__ fuw,
                                               const float* __restrict__ trw,
                                               const float* __restrict__ trb,
                                               const float* __restrict__ p1w,
                                               float* __restrict__ T,
                                               float* __restrict__ TB,
                                               ushort* __restrict__ Bw,
                                               ushort* __restrict__ Bp,
                                               int* __restrict__ offp) {
  int i = blockIdx.x * 256 + threadIdx.x;
  if (i < 5346) {  // T
    int o = i / 81, a = (i / 9) % 9, s = i % 9;
    float acc = 0.f;
    for (int cp = 0; cp < 66; ++cp)
      acc += fuw[(o * 132 + 66 + cp) * 9 + a] *
             (trw[(cp * 3) * 9 + s] + trw[(cp * 3 + 1) * 9 + s] + trw[(cp * 3 + 2) * 9 + s]);
    T[i] = acc; return;
  }
  i -= 5346;
  if (i < 594) {  // TB
    int o = i / 9, a = i % 9;
    float acc = 0.f;
    for (int cp = 0; cp < 66; ++cp) acc += trb[cp] * fuw[(o * 132 + 66 + cp) * 9 + a];
    TB[i] = acc; return;
  }
  i -= 594;
  if (i < 2 * 9 * 80 * 32) {  // Bw
    int cc = i / 23040, t = (i / 2560) % 9, o = (i / 32) % 80, kl = i & 31;
    int c = cc * 32 + kl;
    Bw[i] = (o < 66) ? f2bf(fuw[(o * 132 + c) * 9 + t]) : 0;
    return;
  }
  i -= 2 * 9 * 80 * 32;
  if (i < 12 * 128 * 32) {  // Bp
    int kc = i / 4096, o = (i / 32) % 128, kl = i & 31;
    int k = kc * 32 + kl;
    float v = 0.f;
    if (k < 363) { int u = k / 33, r2 = k % 33, vv = r2 / 3, c = r2 % 3;
                   v = p1w[(o * 3 + c) * 121 + u * 11 + vv]; }
    Bp[i] = f2bf(v);
    return;
  }
  i -= 12 * 128 * 32;
  if (i < 384) {  // offp
    int k = i, off = -1;
    if (k < 363) { int u = k / 33, r2 = k % 33, vv = r2 / 3, c = r2 % 3; off = u * 78 + vv * 3 + c; }
    offp[i] = off;
  }
}

__device__ __forceinline__ float W5val(int o, int d, const float* T) {
  int dy = d / 5, dx = d % 5;
  float acc = 0.f;
  for (int ua = 0; ua < 3; ++ua) {
    int us = dy - ua; if (us < 0 || us > 2) continue;
    for (int va = 0; va < 3; ++va) {
      int vs = dx - va; if (vs < 0 || vs > 2) continue;
      acc += T[(o * 9 + ua * 3 + va) * 9 + us * 3 + vs];
    }
  }
  return acc;
}

// prepB: BwZ (z-chunk weights: xg ch64/65 taps + composed 5x5 W5) and bias_tot
__global__ __launch_bounds__(256) void k_prepB(const float* __restrict__ fuw,
                                               const float* __restrict__ fub,
                                               const float* __restrict__ T,
                                               const float* __restrict__ TB,
                                               ushort* __restrict__ BwZ,
                                               float* __restrict__ bias_tot) {
  int i = blockIdx.x * 256 + threadIdx.x;
  if (i < 5120) {
    int zc = i / 2560, o = (i / 32) % 80, s = i & 31;
    float v = 0.f;
    if (o < 66) {
      if (zc == 0) {
        if (s < 18) { int ch = 64 + s / 9, a = s % 9; v = fuw[(o * 132 + ch) * 9 + a]; }
        else        { v = W5val(o, s - 18, T); }
      } else {
        if (s < 11) v = W5val(o, 14 + s, T);
      }
    }
    BwZ[i] = f2bf(v); return;
  }
  i -= 5120;
  if (i < 80) {
    float v = 0.f;
    if (i < 66) { v = fub[i]; for (int a = 0; a < 9; ++a) v += TB[i * 9 + a]; }
    bias_tot[i] = v;
  }
}

__global__ void k_zero(float* p, int n) {
  int i = blockIdx.x * 256 + threadIdx.x;
  if (i < n) p[i] = 0.f;
}

// ---------------------------------------------------------------------------
// Kernel A: x_gauss NCHW bf16 (unchanged from passing round-1 version)
// ---------------------------------------------------------------------------
__global__ __launch_bounds__(256) void k_xgauss(const float* __restrict__ x,
                                                const float* __restrict__ wg,
                                                __hip_bfloat16* __restrict__ xg) {
  const int bo = blockIdx.z;
  const int b = bo / 66, o = bo % 66;
  const int h0 = blockIdx.y * 8, w0 = blockIdx.x * 128;
  const int g = o / 22;
  const int kidx = o / 3;
  __shared__ float wl[441];
  __shared__ float xt[28 * 148];
  for (int e = threadIdx.x; e < 441; e += 256) wl[e] = wg[o * 441 + e];
  const float* xp = x + (b * 3 + g) * HW;
  for (int e = threadIdx.x; e < 28 * 148; e += 256) {
    int ty = e / 148, tx = e % 148;
    int gy = h0 + ty - 10, gx = w0 + tx - 10;
    xt[e] = (gy >= 0 && gy < HH && gx >= 0 && gx < WW) ? xp[gy * WW + gx] : 0.f;
  }
  __syncthreads();
  int i_ = kidx - 1;
  int im = (i_ - 1 > 0) ? (i_ - 1) : 0;
  int ks = (kidx == 0) ? 1 : 3 + 2 * (im >> 1);
  int p0 = (21 - ks) >> 1;
  const int wq = threadIdx.x & 31, r = threadIdx.x >> 5;
  float a0 = 0.f, a1 = 0.f, a2 = 0.f, a3 = 0.f;
  for (int kh = p0; kh < p0 + ks; ++kh) {
    float rx[24];
    const float4* rp = (const float4*)&xt[(r + kh) * 148 + 4 * wq];
    float4* rv = (float4*)rx;
#pragma unroll
    for (int i = 0; i < 6; i++) rv[i] = rp[i];
    const float* wr = &wl[kh * 21];
#pragma unroll
    for (int kw = 0; kw < 21; kw++) {
      float wv = wr[kw];
      a0 += wv * rx[kw];     a1 += wv * rx[kw + 1];
      a2 += wv * rx[kw + 2]; a3 += wv * rx[kw + 3];
    }
  }
  int oidx = ((b * 66 + o) * HH + (h0 + r)) * WW + w0 + 4 * wq;
  xg[oidx]     = __float2bfloat16(a0);
  xg[oidx + 1] = __float2bfloat16(a1);
  xg[oidx + 2] = __float2bfloat16(a2);
  xg[oidx + 3] = __float2bfloat16(a3);
}

// ---------------------------------------------------------------------------
// Transpose xg NCHW -> NHWC (72-ch padded) for MFMA staging. 64 px per block.
// ---------------------------------------------------------------------------
__global__ __launch_bounds__(256) void k_tr(const ushort* __restrict__ xg,
                                            ushort* __restrict__ xgn) {
  __shared__ ushort ls[64 * 72];
  int p0 = blockIdx.x * 64;
  int b = p0 >> 16, sp = p0 & 65535;
  for (int e = threadIdx.x; e < 72 * 64; e += 256) {
    int c = e >> 6, i = e & 63;
    ls[i * 72 + c] = (c < 66) ? xg[(size_t)(b * 66 + c) * HW + sp + i] : (ushort)0;
  }
  __syncthreads();
  for (int e = threadIdx.x; e < 576; e += 256) {
    *(float4*)(xgn + (size_t)p0 * 72 + e * 8) = *(const float4*)(ls + e * 8);
  }
}

// ---------------------------------------------------------------------------
// Predictor stage 1 as MFMA implicit GEMM: conv 11x11 (3->128, pad 2), then
// leaky + adaptive 3x3 pool (bins all 84x84) via LDS atomics.
// Tile 16x16 conv-out px; M=256 (16 m-tiles), N=128 (8 n-tiles), K=363->384.
// ---------------------------------------------------------------------------
__global__ __launch_bounds__(256, 2) void k_pmm(const float* __restrict__ x,
                                                const ushort* __restrict__ Bp,
                                                const int* __restrict__ offp,
                                                const float* __restrict__ p1b,
                                                float* __restrict__ pooled) {
  __shared__ float xt[26 * 26 * 3];
  __shared__ ushort az[256 * 32];
  __shared__ float ps[1152];
  const int b = blockIdx.z, h0 = blockIdx.y * 16, w0 = blockIdx.x * 16;
  const int tid = threadIdx.x, wave = tid >> 6, lane = tid & 63;
  const int m = lane & 15, q = lane >> 4;
  for (int e = tid; e < 1152; e += 256) ps[e] = 0.f;
  for (int e = tid; e < 676; e += 256) {
    int py = e / 26, pxc = e % 26, gy = h0 - 2 + py, gx = w0 - 2 + pxc;
    bool in = (gy >= 0 && gy < HH && gx >= 0 && gx < WW);
#pragma unroll
    for (int c = 0; c < 3; ++c)
      xt[e * 3 + c] = in ? x[(b * 3 + c) * HW + gy * WW + gx] : 0.f;
  }
  f32x4 acc[4][8];
#pragma unroll
  for (int a = 0; a < 4; ++a)
#pragma unroll
    for (int n = 0; n < 8; ++n) acc[a][n] = (f32x4){0.f, 0.f, 0.f, 0.f};
  const int py = tid >> 4, pxc = tid & 15;
  const int pbase = (py * 26 + pxc) * 3;
  __syncthreads();
  for (int kc = 0; kc < 12; ++kc) {
    union { ushort us[32]; float4 f4[4]; } vals;
#pragma unroll
    for (int kl = 0; kl < 32; ++kl) {
      int off = offp[kc * 32 + kl];  // wave-uniform -> s_load
      vals.us[kl] = f2bf((off >= 0) ? xt[pbase + off] : 0.f);
    }
    if (kc) __syncthreads();
#pragma unroll
    for (int u = 0; u < 4; ++u)
      *(float4*)(az + tid * 32 + ((u ^ (tid & 3)) << 3)) = vals.f4[u];
    __syncthreads();
    bf16x8 bf[8];
#pragma unroll
    for (int nt = 0; nt < 8; ++nt)
      bf[nt] = *(const bf16x8*)(Bp + ((kc * 128 + nt * 16 + m) * 32 + q * 8));
#pragma unroll
    for (int mt = 0; mt < 4; ++mt) {
      int px = (((wave << 2) + mt) << 4) + m;
      bf16x8 af = *(const bf16x8*)(az + px * 32 + ((q ^ (px & 3)) << 3));
#pragma unroll
      for (int nt = 0; nt < 8; ++nt)
        acc[mt][nt] = MFMA16(af, bf[nt], acc[mt][nt]);
    }
  }
  // epilogue: bias + leaky + pool into ps
  float bv[8];
#pragma unroll
  for (int nt = 0; nt < 8; ++nt) bv[nt] = p1b[nt * 16 + m];
#pragma unroll
  for (int mt = 0; mt < 4; ++mt) {
    int h = h0 + (wave << 2) + mt;
    if (h >= 250) continue;
    bool h0m = h < 84, h1m = (h >= 83 && h < 167), h2m = h >= 166;
#pragma unroll
    for (int r = 0; r < 4; ++r) {
      int w = w0 + (q << 2) + r;
      if (w >= 250) continue;
      bool w0m = w < 84, w1m = (w >= 83 && w < 167), w2m = w >= 166;
#pragma unroll
      for (int nt = 0; nt < 8; ++nt) {
        int o = (nt << 4) + m;
        float vz = acc[mt][nt][r] + bv[nt];
        vz = vz >= 0.f ? vz : 0.2f * vz;
        if (h0m) { if (w0m) atomicAdd(&ps[o], vz);        if (w1m) atomicAdd(&ps[128 + o], vz);
                   if (w2m) atomicAdd(&ps[256 + o], vz); }
        if (h1m) { if (w0m) atomicAdd(&ps[384 + o], vz);  if (w1m) atomicAdd(&ps[512 + o], vz);
                   if (w2m) atomicAdd(&ps[640 + o], vz); }
        if (h2m) { if (w0m) atomicAdd(&ps[768 + o], vz);  if (w1m) atomicAdd(&ps[896 + o], vz);
                   if (w2m) atomicAdd(&ps[1024 + o], vz); }
      }
    }
  }
  __syncthreads();
  for (int e = tid; e < 1152; e += 256)
    atomicAdd(&pooled[b * 1152 + e], ps[(e % 9) * 128 + (e / 9)]);
}

// ---------------------------------------------------------------------------
// Predictor tail (pooled now holds SUMS -> scale by 1/7056)
// ---------------------------------------------------------------------------
__global__ __launch_bounds__(256) void k_pred2(const float* __restrict__ pooled,
                                               const float* __restrict__ p2w,
                                               const float* __restrict__ p3w,
                                               float* __restrict__ kernw) {
  const int b = blockIdx.x;
  const int tid = threadIdx.x;
  __shared__ float hin[1152];
  __shared__ float h2p[1323];
  __shared__ float h3l[1323];
  __shared__ float mx[3], sm[3];
  for (int e = tid; e < 1152; e += 256) hin[e] = pooled[b * 1152 + e] * (1.f / 7056.f);
  __syncthreads();
  for (int c = tid; c < 441; c += 256) {
    float z[9] = {0.f,0.f,0.f,0.f,0.f,0.f,0.f,0.f,0.f};
    const float* wr = p2w + c * 128;
    for (int k = 0; k < 128; k++) {
      float wv = wr[k];
      const float* hp = &hin[k * 9];
#pragma unroll
      for (int p = 0; p < 9; p++) z[p] += wv * hp[p];
    }
#pragma unroll
    for (int i = 0; i < 3; i++) {
      float s = 0.f;
#pragma unroll
      for (int jj = 0; jj < 3; jj++) {
        float zz = z[i * 3 + jj];
        s += (zz >= 0.f) ? zz : 0.2f * zz;
      }
      h2p[c * 3 + i] = s * (1.f / 3.f);
    }
  }
  __syncthreads();
  for (int c = tid; c < 441; c += 256) {
    float a0 = 0.f, a1 = 0.f, a2 = 0.f;
    const float* wr = p3w + c * 441;
    for (int k = 0; k < 441; k++) {
      float wv = wr[k];
      a0 += wv * h2p[k * 3];
      a1 += wv * h2p[k * 3 + 1];
      a2 += wv * h2p[k * 3 + 2];
    }
    h3l[c * 3] = a0; h3l[c * 3 + 1] = a1; h3l[c * 3 + 2] = a2;
  }
  __syncthreads();
  if (tid < 3) {
    float mxv = -1e30f;
    for (int c = 0; c < 441; c++) mxv = fmaxf(mxv, h3l[c * 3 + tid]);
    float s = 0.f;
    for (int c = 0; c < 441; c++) s += expf(h3l[c * 3 + tid] - mxv);
    mx[tid] = mxv; sm[tid] = 1.f / s;
  }
  __syncthreads();
  for (int f = tid; f < 1323; f += 256) {
    int i = f % 3;
    kernw[b * 1323 + f] = expf(h3l[f] - mx[i]) * sm[i];
  }
}

// ---------------------------------------------------------------------------
// Kernel D: per-sample dynamic conv (unchanged)
// ---------------------------------------------------------------------------
__global__ __launch_bounds__(256) void k_dyn(const float* __restrict__ x,
                                             const float* __restrict__ kernw,
                                             float* __restrict__ out1) {
  const int b = blockIdx.z;
  const int h0 = blockIdx.y * 16, w0 = blockIdx.x * 64;
  __shared__ float kl[1323];
  __shared__ float xt[3 * 36 * 84];
  for (int e = threadIdx.x; e < 1323; e += 256) kl[e] = kernw[b * 1323 + e];
  for (int e = threadIdx.x; e < 3 * 36 * 84; e += 256) {
    int ci = e / 3024, rem = e % 3024;
    int ty = rem / 84, tx = rem % 84;
    int gy = h0 + ty - 10, gx = w0 + tx - 10;
    xt[e] = (gy >= 0 && gy < HH && gx >= 0 && gx < WW)
                ? x[(b * 3 + ci) * HW + gy * WW + gx] : 0.f;
  }
  __syncthreads();
  const int wq = threadIdx.x & 15, r = threadIdx.x >> 4;
  float a0 = 0.f, a1 = 0.f, a2 = 0.f, a3 = 0.f;
  for (int ci = 0; ci < 3; ci++) {
    for (int kh = 0; kh < 21; kh++) {
      float rx[24];
      const float4* rp = (const float4*)&xt[ci * 3024 + (r + kh) * 84 + 4 * wq];
      float4* rv = (float4*)rx;
#pragma unroll
      for (int i = 0; i < 6; i++) rv[i] = rp[i];
      const float* wr = &kl[ci * 441 + kh * 21];
#pragma unroll
      for (int kw = 0; kw < 21; kw++) {
        float wv = wr[kw];
        a0 += wv * rx[kw];     a1 += wv * rx[kw + 1];
        a2 += wv * rx[kw + 2]; a3 += wv * rx[kw + 3];
      }
    }
  }
  int idx = b * HW + (h0 + r) * WW + w0 + 4 * wq;
  *(float4*)&out1[idx] = make_float4(a0, a1, a2, a3);
}

// ---------------------------------------------------------------------------
// Kernel E: ax_out (unchanged)
// ---------------------------------------------------------------------------
__global__ __launch_bounds__(256) void k_ax(const float* __restrict__ x,
                                            const float* __restrict__ csw,
                                            const float* __restrict__ csb,
                                            float* __restrict__ out2) {
  int idx = blockIdx.x * 256 + threadIdx.x;
  if (idx >= BB * 3 * HW) return;
  int w = idx & 255, h = (idx >> 8) & 255;
  int oc = (idx >> 16) % 3, b = idx / (3 * HW);
  float acc = csb[oc];
  for (int ic = 0; ic < 3; ic++) {
    const float* xc = x + (b * 3 + ic) * HW;
    const float* wp = csw + (oc * 3 + ic) * 9;
#pragma unroll
    for (int u = 0; u < 3; u++) {
      int iy = h + u - 1;
      if (iy < 0 || iy >= HH) continue;
#pragma unroll
      for (int v = 0; v < 3; v++) {
        int ix = w + v - 1;
        if (ix >= 0 && ix < WW) acc += xc[iy * WW + ix] * wp[u * 3 + v];
      }
    }
  }
  out2[idx] = acc;
}

// ---------------------------------------------------------------------------
// Fused conv as MFMA implicit GEMM.
// Tile 16x16 px, N=80 (66 padded). K-steps: 2 chunks (ch0-31,32-63) x 9 taps
// from NHWC LDS tile, + 2 im2col "Z" chunks (ch64/65 x 9 taps, composed 5x5
// out1 taps). Epilogue: LDS transpose for coalesced NCHW stores + bias_tot.
// ---------------------------------------------------------------------------
__global__ __launch_bounds__(256, 3) void k_fmma(const ushort* __restrict__ xgn,
                                                 const float* __restrict__ out1,
                                                 const ushort* __restrict__ Bw,
                                                 const ushort* __restrict__ BwZ,
                                                 const float* __restrict__ bias_tot,
                                                 float* __restrict__ outf) {
  __shared__ __align__(16) char smem[40080];
  ushort* xs  = (ushort*)smem;               // 18*18*32 bf16 = 20736
  float*  o1s = (float*)(smem + 20736);      // 20*20 f32     = 1600
  ushort* xs2 = (ushort*)(smem + 22336);     // 18*18*2 bf16  = 1296
  ushort* az  = (ushort*)(smem + 23632);     // 256*32 bf16   = 16384
  float*  st  = (float*)(smem + 23632);      // 16*257 f32    = 16448 (aliases az)
  const int b = blockIdx.z, h0 = blockIdx.y * 16, w0 = blockIdx.x * 16;
  const int tid = threadIdx.x, wave = tid >> 6, lane = tid & 63;
  const int m = lane & 15, q = lane >> 4;
  f32x4 acc[4][5];
#pragma unroll
  for (int a = 0; a < 4; ++a)
#pragma unroll
    for (int n = 0; n < 5; ++n) acc[a][n] = (f32x4){0.f, 0.f, 0.f, 0.f};

  for (int cc = 0; cc < 2; ++cc) {
    __syncthreads();
    for (int e = tid; e < 1296; e += 256) {
      int u = e & 3, p = e >> 2, py = p / 18, px = p % 18;
      int gy = h0 - 1 + py, gx = w0 - 1 + px;
      float4 v = make_float4(0.f, 0.f, 0.f, 0.f);
      if (gy >= 0 && gy < HH && gx >= 0 && gx < WW)
        v = *(const float4*)(xgn + (size_t)(b * HW + gy * WW + gx) * 72 + cc * 32 + u * 8);
      *(float4*)(xs + p * 32 + u * 8) = v;
    }
    __syncthreads();
#pragma unroll
    for (int t = 0; t < 9; ++t) {
      const int u = t / 3, v = t % 3;
      bf16x8 bf[5];
#pragma unroll
      for (int nt = 0; nt < 5; ++nt)
        bf[nt] = *(const bf16x8*)(Bw + (((cc * 9 + t) * 80 + nt * 16 + m) * 32 + q * 8));
#pragma unroll
      for (int mt = 0; mt < 4; ++mt) {
        int row = (wave << 2) + mt;
        bf16x8 af = *(const bf16x8*)(xs + ((row + u) * 18 + m + v) * 32 + q * 8);
#pragma unroll
        for (int nt = 0; nt < 5; ++nt)
          acc[mt][nt] = MFMA16(af, bf[nt], acc[mt][nt]);
      }
    }
  }
  // stage xg ch64/65 halo tile and out1 tile (2-halo)
  __syncthreads();
  for (int e = tid; e < 324; e += 256) {
    int py = e / 18, px = e % 18, gy = h0 - 1 + py, gx = w0 - 1 + px;
    uint32_t v = 0;
    if (gy >= 0 && gy < HH && gx >= 0 && gx < WW)
      v = *(const uint32_t*)(xgn + (size_t)(b * HW + gy * WW + gx) * 72 + 64);
    *(uint32_t*)(xs2 + e * 2) = v;
  }
  for (int e = tid; e < 400; e += 256) {
    int py = e / 20, px = e % 20, gy = h0 - 2 + py, gx = w0 - 2 + px;
    o1s[e] = (gy >= 0 && gy < HH && gx >= 0 && gx < WW) ? out1[b * HW + gy * WW + gx] : 0.f;
  }
  __syncthreads();
  const int bpy = tid >> 4, bpx = tid & 15;
#pragma unroll
  for (int zc = 0; zc < 2; ++zc) {
    union { ushort us[32]; float4 f4[4]; } vals;
    if (zc == 0) {
#pragma unroll
      for (int s = 0; s < 18; ++s) {
        int ch = s / 9, a = s % 9, u = a / 3, v = a % 3;
        vals.us[s] = xs2[((bpy + u) * 18 + bpx + v) * 2 + ch];
      }
#pragma unroll
      for (int d = 0; d < 14; ++d)
        vals.us[18 + d] = f2bf(o1s[(bpy + d / 5) * 20 + bpx + d % 5]);
    } else {
#pragma unroll
      for (int s = 0; s < 11; ++s) {
        int d = 14 + s;
        vals.us[s] = f2bf(o1s[(bpy + d / 5) * 20 + bpx + d % 5]);
      }
#pragma unroll
      for (int s = 11; s < 32; ++s) vals.us[s] = 0;
    }
    __syncthreads();
#pragma unroll
    for (int u = 0; u < 4; ++u)
      *(float4*)(az + tid * 32 + ((u ^ (tid & 3)) << 3)) = vals.f4[u];
    __syncthreads();
    bf16x8 bf[5];
#pragma unroll
    for (int nt = 0; nt < 5; ++nt)
      bf[nt] = *(const bf16x8*)(BwZ + ((zc * 80 + nt * 16 + m) * 32 + q * 8));
#pragma unroll
    for (int mt = 0; mt < 4; ++mt) {
      int px = (((wave << 2) + mt) << 4) + m;
      bf16x8 af = *(const bf16x8*)(az + px * 32 + ((q ^ (px & 3)) << 3));
#pragma unroll
      for (int nt = 0; nt < 5; ++nt)
        acc[mt][nt] = MFMA16(af, bf[nt], acc[mt][nt]);
    }
  }
  // epilogue: per n-tile, transpose via LDS and store coalesced NCHW + bias
#pragma unroll 1
  for (int nt = 0; nt < 5; ++nt) {
    __syncthreads();
#pragma unroll
    for (int mt = 0; mt < 4; ++mt) {
      int pxb = (((wave << 2) + mt) << 4);
#pragma unroll
      for (int r = 0; r < 4; ++r)
        st[m * 257 + pxb + q * 4 + r] = acc[mt][nt][r];
    }
    __syncthreads();
#pragma unroll
    for (int kk = 0; kk < 16; ++kk) {
      int o = nt * 16 + kk;
      if (o < 66) {
        float bvv = bias_tot[o];
        outf[((b * 66 + o) * HH + h0 + (tid >> 4)) * WW + w0 + (tid & 15)] =
            st[kk * 257 + tid] + bvv;
      }
    }
  }
}

// ---------------------------------------------------------------------------
// Border fixup for the composed out1 path: subtract invalid-q contributions.
// ---------------------------------------------------------------------------
__global__ __launch_bounds__(256) void k_fix(const float* __restrict__ out1,
                                             const float* __restrict__ T,
                                             const float* __restrict__ TB,
                                             float* __restrict__ outf) {
  int idx = blockIdx.x * 256 + threadIdx.x;
  if (idx >= 8 * 1020 * 66) return;
  int b = idx / (1020 * 66);
  int rem = idx % (1020 * 66);
  int pi = rem / 66, o = rem % 66;
  int ph, pw;
  if (pi < 256)      { ph = 0;        pw = pi; }
  else if (pi < 512) { ph = 255;      pw = pi - 256; }
  else if (pi < 766) { ph = pi - 511; pw = 0; }
  else               { ph = pi - 765; pw = 255; }
  float corr = 0.f;
#pragma unroll
  for (int a = 0; a < 9; ++a) {
    int ua = a / 3, va = a % 3;
    int qh = ph + ua - 1, qw = pw + va - 1;
    if (qh >= 0 && qh < HH && qw >= 0 && qw < WW) continue;
    float s = TB[o * 9 + a];
#pragma unroll
    for (int t2 = 0; t2 < 9; ++t2) {
      int rh = qh + t2 / 3 - 1, rw = qw + t2 % 3 - 1;
      if (rh >= 0 && rh < HH && rw >= 0 && rw < WW)
        s += out1[b * HW + rh * WW + rw] * T[(o * 9 + a) * 9 + t2];
    }
    corr += s;
  }
  outf[((b * 66 + o) * HH + ph) * WW + pw] -= corr;
}

// ---------------------------------------------------------------------------
extern "C" void kernel_launch(void* const* d_in, const int* in_sizes, int n_in,
                              void* d_out, int out_size, void* d_ws, size_t ws_size,
                              hipStream_t stream) {
  const float* x   = (const float*)d_in[0];
  const float* wg  = (const float*)d_in[1];
  const float* p1w = (const float*)d_in[2];
  const float* p1b = (const float*)d_in[3];
  const float* p2w = (const float*)d_in[4];
  const float* p3w = (const float*)d_in[5];
  const float* csw = (const float*)d_in[6];
  const float* csb = (const float*)d_in[7];
  const float* trw = (const float*)d_in[8];
  const float* trb = (const float*)d_in[9];
  const float* fuw = (const float*)d_in[10];
  const float* fub = (const float*)d_in[11];
  float* outf = (float*)d_out;                 // fused: 8*66*256*256
  float* out2 = outf + 34603008;               // ax_out: 8*3*256*256
  char* ws = (char*)d_ws;
  __hip_bfloat16* xg = (__hip_bfloat16*)(ws + OFF_XG);
  ushort* xgn    = (ushort*)(ws + OFF_XGN);
  float* out1    = (float*)(ws + OFF_OUT1);
  float* pooled  = (float*)(ws + OFF_POOL);
  float* kernw   = (float*)(ws + OFF_KERN);
  ushort* Bw     = (ushort*)(ws + OFF_BW);
  ushort* BwZ    = (ushort*)(ws + OFF_BWZ);
  ushort* Bp     = (ushort*)(ws + OFF_BP);
  float* biasT   = (float*)(ws + OFF_BIAS);
  float* TBp     = (float*)(ws + OFF_TB);
  float* Tp      = (float*)(ws + OFF_T);
  int*   offp    = (int*)(ws + OFF_OFFP);

  hipLaunchKernelGGL(k_prepA, dim3(397), dim3(256), 0, stream,
                     fuw, trw, trb, p1w, Tp, TBp, Bw, Bp, offp);
  hipLaunchKernelGGL(k_prepB, dim3(21), dim3(256), 0, stream,
                     fuw, fub, Tp, TBp, BwZ, biasT);
  hipLaunchKernelGGL(k_zero, dim3(36), dim3(256), 0, stream, pooled, 9216);
  hipLaunchKernelGGL(k_xgauss, dim3(2, 32, 8 * 66), dim3(256), 0, stream, x, wg, xg);
  hipLaunchKernelGGL(k_tr, dim3(8192), dim3(256), 0, stream, (const ushort*)xg, xgn);
  hipLaunchKernelGGL(k_pmm, dim3(16, 16, 8), dim3(256), 0, stream, x, Bp, offp, p1b, pooled);
  hipLaunchKernelGGL(k_pred2, dim3(8), dim3(256), 0, stream, pooled, p2w, p3w, kernw);
  hipLaunchKernelGGL(k_dyn, dim3(4, 16, 8), dim3(256), 0, stream, x, kernw, out1);
  hipLaunchKernelGGL(k_fmma, dim3(16, 16, 8), dim3(256), 0, stream,
                     xgn, out1, Bw, BwZ, biasT, outf);
  hipLaunchKernelGGL(k_fix, dim3(2104), dim3(256), 0, stream, out1, Tp, TBp, outf);
  hipLaunchKernelGGL(k_ax, dim3(6144), dim3(256), 0, stream, x, csw, csb, out2);
}